// Round 5
// baseline (239.173 us; speedup 1.0000x reference)
//
#include <hip/hip_runtime.h>
#include <hip/hip_cooperative_groups.h>

namespace cg = cooperative_groups;

// Predictive-coding graph message passing, MI355X — round 15.
// R14 (107.5us) = 41.4us structural workspace poison + ~66us of FIVE
// dispatches + four launch gaps. Phase traffic arithmetic puts the pure-BW
// floor of the kernel work at ~8-10us; the biggest remaining expendable
// slice is launch/gap overhead (~15-20us) plus inter-phase re-reads.
// R15: single cooperative kernel (256 blocks x 1024 thr = 1 block/CU,
// 88 KB LDS union — co-residency exact). grid.sync() between phases.
//   P1: stage chunk edges in LDS (persist across syncs!) + dual 256-bin hist.
//   P2: blocks 0-1 scan the [chunk][bucket] count matrix; blocks 2-65 do
//       the transpose/tanh — overlapped, previously separate work.
//   P3: scatter both dirs from the LDS stage (zero global edge re-reads).
//   P4/P5: per-bucket fine sort + select-free pipelined accumulation
//          (unchanged from R14), mu/eps then dx.

static constexpr int kB = 32, kLogB = 5;
static constexpr int kBkt = 256;        // coarse buckets (16 nodes each)
static constexpr int kNPB = 16;         // nodes per bucket
static constexpr int kChunk = 2048;     // edges per chunk block
static constexpr int kTile = 2560;      // pass LDS tile (mean 2048, +11sigma)
static constexpr int kGrid = 256;       // 1 block per CU, cooperative

// ---- per-bucket fine sort + select-free pipelined accumulation ----------
__device__ __forceinline__ void pass_phase(
    const uint2* __restrict__ rec, const unsigned* __restrict__ seg,
    const float* __restrict__ vals, const float* __restrict__ x_t,
    const float* __restrict__ fx_t, float* __restrict__ eps_t,
    float* __restrict__ out, int N, int mode, int t, int tid,
    uint2* srt, unsigned* hW, unsigned* wbase, unsigned* wcur,
    unsigned* h, unsigned* hb, float* red) {
  int segb = (int)seg[t], sege = (int)seg[t + 1];
  int wv = tid >> 6;
  int b = tid & 31, hw = tid >> 5, l = hw >> 1, part = hw & 1;
  float acc = 0.0f;

  for (int t0 = segb; t0 < sege; t0 += kTile) {    // 1 tile except 11-sigma tail
    int len = min(kTile, sege - t0);
    if (tid < 16 * kNPB) { hW[tid] = 0u; wcur[tid] = 0u; }
    __syncthreads();
    for (int i = tid; i < len; i += 1024)          // privatized 16-bin hist
      atomicAdd(&hW[wv * kNPB + (rec[t0 + i].x & 15u)], 1u);
    __syncthreads();
    if (tid < kNPB) {                              // cross-wave prefix per node
      unsigned run = 0;
#pragma unroll
      for (int w2 = 0; w2 < 16; ++w2) {
        unsigned c = hW[w2 * kNPB + tid];
        wbase[w2 * kNPB + tid] = run;
        run += c;
      }
      h[tid] = run;
    }
    __syncthreads();
    if (tid == 0) {                                // 16-elem excl scan
      unsigned run = 0;
#pragma unroll
      for (int l2 = 0; l2 < kNPB; ++l2) { hb[l2] = run; run += h[l2]; }
    }
    __syncthreads();
    if (tid < 16 * kNPB) wbase[tid] += hb[tid & (kNPB - 1)];
    __syncthreads();
    for (int i = tid; i < len; i += 1024) {        // fine sort (per-wave cursors)
      uint2 r = rec[t0 + i];
      unsigned lx = r.x & 15u;
      srt[wbase[wv * kNPB + lx] + atomicAdd(&wcur[wv * kNPB + lx], 1u)] = r;
    }
    __syncthreads();

    int beg = (int)hb[l] + part, end = (int)hb[l] + (int)h[l];
    int last = end - 1; if (last < 0) last = 0;
    uint2 r0, r1, r2, r3, r4, r5, r6, r7;
    float v0, v1, v2, v3, v4, v5, v6, v7;
    // Select-free pipeline: loads unconditional with clamped index; only the
    // WEIGHT is predicated (integer test) -> 8 gathers stay in flight.
#define PC_LOAD(d)                                                   \
    { int p = beg + 2 * (d); uint2 rr = srt[min(p, last)];           \
      r##d = rr; v##d = vals[(((rr.x >> 4) & 4095u) << kLogB) + b]; }
    PC_LOAD(0) PC_LOAD(1) PC_LOAD(2) PC_LOAD(3)
    PC_LOAD(4) PC_LOAD(5) PC_LOAD(6) PC_LOAD(7)
#undef PC_LOAD
    int i = beg;
    while (i < end) {
#define PC_STEP(d)                                                   \
      { float wt = (i + 2 * (d) < end) ? __uint_as_float(r##d.y) : 0.0f; \
        acc = fmaf(wt, v##d, acc);                                   \
        int p = i + 16 + 2 * (d); uint2 rr = srt[min(p, last)];      \
        r##d = rr; v##d = vals[(((rr.x >> 4) & 4095u) << kLogB) + b]; }
      PC_STEP(0) PC_STEP(1) PC_STEP(2) PC_STEP(3)
      PC_STEP(4) PC_STEP(5) PC_STEP(6) PC_STEP(7)
#undef PC_STEP
      i += 16;
    }
    __syncthreads();                               // srt/hW reused next tile
  }

  red[tid] = acc;
  __syncthreads();
  if (part == 0) {                                 // combine 2 parts, write
    float s = red[tid] + red[tid + 32];
    int n = t * kNPB + l;
    int j = (n << kLogB) + b;
    if (mode == 0) {
      out[b * N + n] = s;                          // mu: 16 nodes = full 64B line
      eps_t[j] = x_t[j] - s;
    } else {
      float fx = fx_t[j];
      out[b * N + n] = fmaf(1.0f - fx * fx, s, -eps_t[j]);  // dx
    }
  }
  __syncthreads();                                 // red reused by next phase
}

__global__ void __launch_bounds__(1024) k_fused(
    const float* __restrict__ x, const float* __restrict__ w,
    const int* __restrict__ esrc, const int* __restrict__ edst,
    float* __restrict__ x_t, float* __restrict__ fx_t,
    float* __restrict__ eps_t,
    unsigned* __restrict__ cntA, unsigned* __restrict__ cntB,
    unsigned* __restrict__ baseA, unsigned* __restrict__ baseB,
    unsigned* __restrict__ segA, unsigned* __restrict__ segB,
    uint2* __restrict__ recA, uint2* __restrict__ recB,
    float* __restrict__ out_mu, float* __restrict__ out_dx,
    int N, int E, int nBB) {
  cg::grid_group grid = cg::this_grid();

  __shared__ int sS[kChunk], sD[kChunk];           // 16 KB staged edge ids
  __shared__ float sW[kChunk];                     // 8 KB staged weights
  __shared__ unsigned hA[kBkt], hB[kBkt];          // chunk histograms
  __shared__ unsigned qoff[4][kBkt], tot[kBkt], bbx[kBkt];   // scan
  __shared__ float tile[32][65];                   // transpose
  __shared__ unsigned myBase[kBkt], baseL[kBkt], cnt2[kBkt]; // scatter
  __shared__ uint2 cmp[kChunk];                    // 16 KB chunk-sorted
  __shared__ unsigned char bktid[kChunk];
  __shared__ uint2 srt[kTile];                     // 20 KB pass sort
  __shared__ unsigned hW[16 * kNPB], wbase[16 * kNPB], wcur[16 * kNPB];
  __shared__ unsigned h[kNPB], hb[kNPB];
  __shared__ float red[1024];

  int tid = threadIdx.x, blk = blockIdx.x;

  // ---- P1: stage chunk edges + dual histogram (LDS persists to P3). -----
  if (blk < nBB) {
    if (tid < kBkt) { hA[tid] = 0u; hB[tid] = 0u; }
    __syncthreads();
    int e0 = blk * kChunk, len = min(kChunk, E - e0);
    for (int i = tid; i < len; i += 1024) {
      int s = esrc[e0 + i], d = edst[e0 + i];
      sS[i] = s; sD[i] = d; sW[i] = w[e0 + i];
      atomicAdd(&hA[((unsigned)d) >> 4], 1u);      // ~8/bin: cheap
      atomicAdd(&hB[((unsigned)s) >> 4], 1u);
    }
    __syncthreads();
    if (tid < kBkt) {                              // non-atomic row write
      cntA[(size_t)blk * kBkt + tid] = hA[tid];
      cntB[(size_t)blk * kBkt + tid] = hB[tid];
    }
  }
  grid.sync();

  // ---- P2: blocks 0-1 scan count matrix; blocks 2-65 transpose/tanh. ----
  if (blk < 2) {
    const unsigned* cnt = blk ? cntB : cntA;
    unsigned* base = blk ? baseB : baseA;
    unsigned* seg  = blk ? segB  : segA;
    int t = tid & (kBkt - 1), q = tid >> 8;
    int qlen = (nBB + 3) >> 2;
    int b0 = q * qlen;
    unsigned run = 0;
    for (int j = 0; j < qlen; j += 8) {
      unsigned c[8];
#pragma unroll
      for (int u = 0; u < 8; ++u) {                // 8 loads in flight
        int bi = b0 + j + u;
        c[u] = (bi < nBB) ? cnt[(size_t)bi * kBkt + t] : 0u;
      }
#pragma unroll
      for (int u = 0; u < 8; ++u) run += c[u];
    }
    qoff[q][t] = run;
    __syncthreads();
    unsigned myTot = 0;
    if (tid < kBkt) {                              // quarter offsets + totals
      unsigned p0 = qoff[0][tid], p1 = qoff[1][tid];
      unsigned p2 = qoff[2][tid], p3 = qoff[3][tid];
      qoff[0][tid] = 0u; qoff[1][tid] = p0;
      qoff[2][tid] = p0 + p1; qoff[3][tid] = p0 + p1 + p2;
      myTot = p0 + p1 + p2 + p3;
      tot[tid] = myTot;
    }
    __syncthreads();
    for (int o = 1; o < kBkt; o <<= 1) {           // Hillis-Steele, 256 totals
      unsigned v = 0;
      if (tid < kBkt && tid >= o) v = tot[tid - o];
      __syncthreads();
      if (tid < kBkt && tid >= o) tot[tid] += v;
      __syncthreads();
    }
    if (tid < kBkt) {
      unsigned excl = tot[tid] - myTot;
      bbx[tid] = excl;
      seg[tid] = excl;                             // dense segment starts
      if (tid == kBkt - 1) seg[kBkt] = excl + myTot;
    }
    __syncthreads();
    run = bbx[t] + qoff[q][t];                     // replay: absolute bases
    for (int j = 0; j < qlen; j += 8) {
      unsigned c[8];
#pragma unroll
      for (int u = 0; u < 8; ++u) {
        int bi = b0 + j + u;
        c[u] = (bi < nBB) ? cnt[(size_t)bi * kBkt + t] : 0u;
      }
#pragma unroll
      for (int u = 0; u < 8; ++u) {
        int bi = b0 + j + u;
        if (bi < nBB) base[(size_t)bi * kBkt + t] = run;
        run += c[u];
      }
    }
  } else if (blk - 2 < (N >> 6)) {
    int n0 = (blk - 2) * 64;
    for (int k = tid; k < 32 * 64; k += 1024) {    // coalesced 256B rows
      int b = k >> 6, n = k & 63;
      tile[b][n] = x[b * N + n0 + n];
    }
    __syncthreads();
    for (int k = tid; k < 64 * 32; k += 1024) {    // coalesced t-layout
      int n = k >> 5, b = k & 31;
      float xv = tile[b][n];
      int j = (n0 + n) * kB + b;
      x_t[j] = xv;
      fx_t[j] = tanhf(xv);
    }
  }
  grid.sync();

  // ---- P3: scatter both dirs from LDS stage (hA/hB still live). ---------
  if (blk < nBB) {
    int e0 = blk * kChunk, len = min(kChunk, E - e0);
    for (int dir = 0; dir < 2; ++dir) {
      const int* key = dir ? sS : sD;              // A: by dst, B: by src
      const int* oth = dir ? sD : sS;
      const unsigned* hst = dir ? hB : hA;
      const unsigned* base = dir ? baseB : baseA;
      uint2* out = dir ? recB : recA;
      if (tid < kBkt) {
        myBase[tid] = base[(size_t)blk * kBkt + tid];
        cnt2[tid] = 0u;
      }
      __syncthreads();
      if (tid < 64) {                              // single-wave excl scan
        int qq = tid << 2;
        unsigned c0 = hst[qq], c1 = hst[qq + 1];
        unsigned c2 = hst[qq + 2], c3 = hst[qq + 3];
        unsigned s = c0 + c1 + c2 + c3, run = s;
#pragma unroll
        for (int o = 1; o < 64; o <<= 1) {
          unsigned v = __shfl_up(run, o, 64);
          if (tid >= o) run += v;
        }
        unsigned bse = run - s;
        baseL[qq] = bse; baseL[qq + 1] = bse + c0;
        baseL[qq + 2] = bse + c0 + c1; baseL[qq + 3] = bse + c0 + c1 + c2;
      }
      __syncthreads();
      for (int i = tid; i < len; i += 1024) {      // LDS sort
        unsigned ky = (unsigned)key[i], ot = (unsigned)oth[i];
        unsigned bbk = ky >> 4;
        unsigned slot = baseL[bbk] + atomicAdd(&cnt2[bbk], 1u);
        cmp[slot] = make_uint2((ot << 4) | (ky & 15u), __float_as_uint(sW[i]));
        bktid[slot] = (unsigned char)bbk;
      }
      __syncthreads();
      for (int s2 = tid; s2 < len; s2 += 1024) {   // coalesced run copy-out
        unsigned bbk = bktid[s2];
        out[myBase[bbk] + ((unsigned)s2 - baseL[bbk])] = cmp[s2];
      }
      __syncthreads();
    }
  }
  grid.sync();

  // ---- P4: pass1 — mu[n] = sum w*fx[src]; eps = x - mu. -----------------
  pass_phase(recA, segA, fx_t, x_t, fx_t, eps_t, out_mu, N, 0, blk, tid,
             srt, hW, wbase, wcur, h, hb, red);
  grid.sync();

  // ---- P5: pass2 — dx[n] = -eps[n] + f'(x_n) * sum w*eps[dst]. ----------
  pass_phase(recB, segB, eps_t, x_t, fx_t, eps_t, out_dx, N, 1, blk, tid,
             srt, hW, wbase, wcur, h, hb, red);
}

extern "C" void kernel_launch(void* const* d_in, const int* in_sizes, int n_in,
                              void* d_out, int out_size, void* d_ws, size_t ws_size,
                              hipStream_t stream) {
  const float* x    = (const float*)d_in[0];
  const float* w    = (const float*)d_in[1];
  const int*   esrc = (const int*)d_in[2];
  const int*   edst = (const int*)d_in[3];

  int BN = in_sizes[0];                  // 131072
  int E  = in_sizes[1];                  // 524288
  int N  = BN / kB;                      // 4096
  int nBB = (E + kChunk - 1) / kChunk;   // 256

  float* ws    = (float*)d_ws;
  float* x_t   = ws;                     // [BN]
  float* fx_t  = ws + (size_t)BN;        // [BN]
  float* eps_t = ws + 2 * (size_t)BN;    // [BN]
  unsigned* cntA = (unsigned*)(ws + 3 * (size_t)BN);    // [nBB*256] 256 KB
  unsigned* cntB = cntA + (size_t)nBB * kBkt;
  unsigned* baseA = cntB + (size_t)nBB * kBkt;          // [nBB*256]
  unsigned* baseB = baseA + (size_t)nBB * kBkt;
  unsigned* segA = baseB + (size_t)nBB * kBkt;          // [257] (512 pad)
  unsigned* segB = segA + 512;
  uint2* recA = (uint2*)(segB + 512);                   // [E] 4 MB dense
  uint2* recB = recA + (size_t)E;                       // [E] 4 MB dense

  float* out_mu = (float*)d_out;
  float* out_dx = (float*)d_out + BN;

  void* args[] = {
      (void*)&x, (void*)&w, (void*)&esrc, (void*)&edst,
      (void*)&x_t, (void*)&fx_t, (void*)&eps_t,
      (void*)&cntA, (void*)&cntB, (void*)&baseA, (void*)&baseB,
      (void*)&segA, (void*)&segB, (void*)&recA, (void*)&recB,
      (void*)&out_mu, (void*)&out_dx, (void*)&N, (void*)&E, (void*)&nBB};
  hipLaunchCooperativeKernel((void*)k_fused, dim3(kGrid), dim3(1024),
                             args, 0, stream);
}

// Round 6
// 120.636 us; speedup vs baseline: 1.9826x; 1.9826x over previous
//
#include <hip/hip_runtime.h>

// Predictive-coding graph message passing, MI355X — round 16.
// R15 post-mortem: cooperative grid.sync() costs ~25-40us EACH on MI355X
// (8 non-coherent XCD L2s -> global atomic + cache-flush barrier); fusion
// regressed 107->239us. Graph-captured launch gaps are only ~1-2us. So:
// revert to R14's 5-kernel skeleton (best, 107.5us) and shave it:
//  (1) k_scan dispatch deleted — fused into k_hist via deterministic
//      LAST-BLOCK pattern (no spinning: last two arrivals each scan one
//      direction while the grid drains). 5 dispatches -> 4.
//  (2) k_pass stages records into LDS once (R14 re-read rec[] from global
//      in the fine-sort loop: 4MB extra per pass). Hist+sort now read LDS.
// Everything else identical to R14 (verified 107.5us, absmax 4.9e-4).

static constexpr int kB = 32, kLogB = 5;
static constexpr int kBkt = 256;        // coarse buckets (16 nodes each)
static constexpr int kNPB = 16;         // nodes per bucket
static constexpr int kChunk = 2048;     // edges per chunk block
static constexpr int kTile = 2560;      // pass LDS tile (mean 2048, +11sigma)

// ---- K1: per-chunk dual histograms + transpose/tanh + last-block scan. --
__global__ void __launch_bounds__(1024) k_hist(
    const int* __restrict__ esrc, const int* __restrict__ edst,
    const float* __restrict__ x, float* __restrict__ x_t,
    float* __restrict__ fx_t, unsigned* __restrict__ cntA,
    unsigned* __restrict__ cntB,
    unsigned* __restrict__ baseA, unsigned* __restrict__ baseB,
    unsigned* __restrict__ segA, unsigned* __restrict__ segB,
    unsigned* __restrict__ ctr, int N, int E, int nBB, int nTotal) {
  __shared__ unsigned hA[kBkt], hB[kBkt];
  __shared__ float tile[32][65];
  __shared__ unsigned qoff[4][kBkt], tot[kBkt], bbx[kBkt];
  __shared__ unsigned rank;
  int tid = threadIdx.x, blk = blockIdx.x;

  if (blk < nBB) {
    if (tid < kBkt) { hA[tid] = 0u; hB[tid] = 0u; }
    __syncthreads();
    int e0 = blk * kChunk, len = min(kChunk, E - e0);
    for (int i = tid; i < len; i += 1024) {
      atomicAdd(&hA[((unsigned)edst[e0 + i]) >> 4], 1u);  // ~8/bin: cheap
      atomicAdd(&hB[((unsigned)esrc[e0 + i]) >> 4], 1u);
    }
    __syncthreads();
    if (tid < kBkt) {                    // non-atomic coalesced row write
      cntA[(size_t)blk * kBkt + tid] = hA[tid];
      cntB[(size_t)blk * kBkt + tid] = hB[tid];
    }
  } else {
    int n0 = (blk - nBB) * 64;
    for (int k = tid; k < 32 * 64; k += 1024) {  // coalesced 256B rows
      int b = k >> 6, n = k & 63;
      tile[b][n] = x[b * N + n0 + n];
    }
    __syncthreads();
    for (int k = tid; k < 64 * 32; k += 1024) {  // coalesced t-layout
      int n = k >> 5, b = k & 31;
      float xv = tile[b][n];
      int j = (n0 + n) * kB + b;
      x_t[j] = xv;
      fx_t[j] = tanhf(xv);
    }
  }

  // ---- last-block scan: last two arrivals each scan one direction. ------
  __syncthreads();
  if (tid == 0) {
    __threadfence();                     // publish this block's cnt rows
    rank = atomicAdd(ctr, 1u);           // device-scope arrival
  }
  __syncthreads();
  int myRank = (int)rank;
  int dir = -1;
  if (myRank == nTotal - 2) dir = 0;     // second-to-last: direction A
  if (myRank == nTotal - 1) dir = 1;     // last: direction B
  if (dir < 0) return;
  __threadfence();                       // acquire: see all cnt rows

  const unsigned* cnt = dir ? cntB : cntA;
  unsigned* base = dir ? baseB : baseA;
  unsigned* seg  = dir ? segB  : segA;
  int t = tid & (kBkt - 1), q = tid >> 8;
  int qlen = (nBB + 3) >> 2;
  int b0 = q * qlen;
  unsigned run = 0;
  for (int j = 0; j < qlen; j += 8) {
    unsigned c[8];
#pragma unroll
    for (int u = 0; u < 8; ++u) {        // 8 loads in flight
      int bi = b0 + j + u;
      c[u] = (bi < nBB) ? cnt[(size_t)bi * kBkt + t] : 0u;
    }
#pragma unroll
    for (int u = 0; u < 8; ++u) run += c[u];
  }
  qoff[q][t] = run;
  __syncthreads();
  unsigned myTot = 0;
  if (tid < kBkt) {                      // quarter offsets + bucket totals
    unsigned p0 = qoff[0][tid], p1 = qoff[1][tid];
    unsigned p2 = qoff[2][tid], p3 = qoff[3][tid];
    qoff[0][tid] = 0u; qoff[1][tid] = p0;
    qoff[2][tid] = p0 + p1; qoff[3][tid] = p0 + p1 + p2;
    myTot = p0 + p1 + p2 + p3;
    tot[tid] = myTot;
  }
  __syncthreads();
  for (int o = 1; o < kBkt; o <<= 1) {   // Hillis-Steele over 256 totals
    unsigned v = 0;
    if (tid < kBkt && tid >= o) v = tot[tid - o];
    __syncthreads();
    if (tid < kBkt && tid >= o) tot[tid] += v;
    __syncthreads();
  }
  if (tid < kBkt) {
    unsigned excl = tot[tid] - myTot;
    bbx[tid] = excl;
    seg[tid] = excl;                     // dense segment starts
    if (tid == kBkt - 1) seg[kBkt] = excl + myTot;
  }
  __syncthreads();
  run = bbx[t] + qoff[q][t];             // replay: absolute bases
  for (int j = 0; j < qlen; j += 8) {
    unsigned c[8];
#pragma unroll
    for (int u = 0; u < 8; ++u) {
      int bi = b0 + j + u;
      c[u] = (bi < nBB) ? cnt[(size_t)bi * kBkt + t] : 0u;
    }
#pragma unroll
    for (int u = 0; u < 8; ++u) {
      int bi = b0 + j + u;
      if (bi < nBB) base[(size_t)bi * kBkt + t] = run;
      run += c[u];
    }
  }
}

// ---- K2: deterministic scatter into dense bucket segments. --------------
__global__ void __launch_bounds__(1024) k_scatter(
    const int* __restrict__ esrc, const int* __restrict__ edst,
    const float* __restrict__ wgt,
    const unsigned* __restrict__ cntA, const unsigned* __restrict__ cntB,
    const unsigned* __restrict__ baseA, const unsigned* __restrict__ baseB,
    uint2* __restrict__ recA, uint2* __restrict__ recB, int E, int nBB) {
  __shared__ unsigned myBase[kBkt], cntL[kBkt], baseL[kBkt], cnt2[kBkt];
  __shared__ uint2 cmp[kChunk];          // 16 KB chunk-sorted records
  __shared__ unsigned char bktid[kChunk];
  int tid = threadIdx.x, blk = blockIdx.x;
  int e0 = blk * kChunk, len = min(kChunk, E - e0);
  for (int dir = 0; dir < 2; ++dir) {
    const int* key = dir ? esrc : edst;  // A: by dst, B: by src
    const int* oth = dir ? edst : esrc;
    const unsigned* cnt = dir ? cntB : cntA;
    const unsigned* base = dir ? baseB : baseA;
    uint2* out = dir ? recB : recA;
    if (tid < kBkt) {
      myBase[tid] = base[(size_t)blk * kBkt + tid];
      cntL[tid] = cnt[(size_t)blk * kBkt + tid];
      cnt2[tid] = 0u;
    }
    __syncthreads();
    if (tid < 64) {                      // single-wave excl scan, 4 bins/lane
      int qq = tid << 2;
      unsigned c0 = cntL[qq], c1 = cntL[qq + 1];
      unsigned c2 = cntL[qq + 2], c3 = cntL[qq + 3];
      unsigned s = c0 + c1 + c2 + c3, run = s;
#pragma unroll
      for (int o = 1; o < 64; o <<= 1) {
        unsigned v = __shfl_up(run, o, 64);
        if (tid >= o) run += v;
      }
      unsigned bse = run - s;
      baseL[qq] = bse; baseL[qq + 1] = bse + c0;
      baseL[qq + 2] = bse + c0 + c1; baseL[qq + 3] = bse + c0 + c1 + c2;
    }
    __syncthreads();
    for (int i = tid; i < len; i += 1024) {        // LDS sort
      unsigned ky = (unsigned)key[e0 + i], ot = (unsigned)oth[e0 + i];
      unsigned bbk = ky >> 4;
      unsigned slot = baseL[bbk] + atomicAdd(&cnt2[bbk], 1u);
      cmp[slot] = make_uint2((ot << 4) | (ky & 15u), __float_as_uint(wgt[e0 + i]));
      bktid[slot] = (unsigned char)bbk;
    }
    __syncthreads();
    for (int s = tid; s < len; s += 1024) {        // coalesced run copy-out
      unsigned bbk = bktid[s];
      out[myBase[bbk] + ((unsigned)s - baseL[bbk])] = cmp[s];
    }
    __syncthreads();
  }
}

// ---- K3/K4: per-bucket fine sort + select-free pipelined accumulation. --
// Records staged into LDS ONCE (R14 re-read global in the sort loop).
// Wave wv owns node l (both parts). Loads unconditional with clamped index;
// only the WEIGHT is predicated (integer test, no memory dependence).
__global__ void __launch_bounds__(1024) k_pass(
    const uint2* __restrict__ rec, const unsigned* __restrict__ seg,
    const float* __restrict__ vals, const float* __restrict__ x_t,
    const float* __restrict__ fx_t, float* __restrict__ eps_t,
    float* __restrict__ out, int N, int mode) {
  __shared__ uint2 stg[kTile];           // 20 KB staged records
  __shared__ uint2 srt[kTile];           // 20 KB node-sorted records
  __shared__ unsigned hW[16 * kNPB];     // per-wave private hist
  __shared__ unsigned wbase[16 * kNPB];  // absolute slot base per (wave,node)
  __shared__ unsigned wcur[16 * kNPB];
  __shared__ unsigned h[kNPB], hb[kNPB];
  __shared__ float red[1024];
  int tid = threadIdx.x, t = blockIdx.x;
  int segb = (int)seg[t], sege = (int)seg[t + 1];
  int wv = tid >> 6;
  int b = tid & 31, hw = tid >> 5, l = hw >> 1, part = hw & 1;
  float acc = 0.0f;

  for (int t0 = segb; t0 < sege; t0 += kTile) {    // 1 tile except 11-sigma tail
    int len = min(kTile, sege - t0);
    if (tid < 16 * kNPB) { hW[tid] = 0u; wcur[tid] = 0u; }
    __syncthreads();
    for (int i = tid; i < len; i += 1024) {        // stage + privatized hist
      uint2 r = rec[t0 + i];
      stg[i] = r;
      atomicAdd(&hW[wv * kNPB + (r.x & 15u)], 1u);
    }
    __syncthreads();
    if (tid < kNPB) {                              // cross-wave prefix per node
      unsigned run = 0;
#pragma unroll
      for (int w2 = 0; w2 < 16; ++w2) {
        unsigned c = hW[w2 * kNPB + tid];
        wbase[w2 * kNPB + tid] = run;
        run += c;
      }
      h[tid] = run;
    }
    __syncthreads();
    if (tid == 0) {                                // 16-elem excl scan
      unsigned run = 0;
#pragma unroll
      for (int l2 = 0; l2 < kNPB; ++l2) { hb[l2] = run; run += h[l2]; }
    }
    __syncthreads();
    if (tid < 16 * kNPB) wbase[tid] += hb[tid & (kNPB - 1)];
    __syncthreads();
    for (int i = tid; i < len; i += 1024) {        // fine sort (LDS -> LDS)
      uint2 r = stg[i];
      unsigned lx = r.x & 15u;
      srt[wbase[wv * kNPB + lx] + atomicAdd(&wcur[wv * kNPB + lx], 1u)] = r;
    }
    __syncthreads();

    int beg = (int)hb[l] + part, end = (int)hb[l] + (int)h[l];
    int last = end - 1; if (last < 0) last = 0;
    uint2 r0, r1, r2, r3, r4, r5, r6, r7;
    float v0, v1, v2, v3, v4, v5, v6, v7;
#define PC_LOAD(d)                                                   \
    { int p = beg + 2 * (d); uint2 rr = srt[min(p, last)];           \
      r##d = rr; v##d = vals[(((rr.x >> 4) & 4095u) << kLogB) + b]; }
    PC_LOAD(0) PC_LOAD(1) PC_LOAD(2) PC_LOAD(3)
    PC_LOAD(4) PC_LOAD(5) PC_LOAD(6) PC_LOAD(7)
#undef PC_LOAD
    int i = beg;
    while (i < end) {
#define PC_STEP(d)                                                   \
      { float wt = (i + 2 * (d) < end) ? __uint_as_float(r##d.y) : 0.0f; \
        acc = fmaf(wt, v##d, acc);                                   \
        int p = i + 16 + 2 * (d); uint2 rr = srt[min(p, last)];      \
        r##d = rr; v##d = vals[(((rr.x >> 4) & 4095u) << kLogB) + b]; }
      PC_STEP(0) PC_STEP(1) PC_STEP(2) PC_STEP(3)
      PC_STEP(4) PC_STEP(5) PC_STEP(6) PC_STEP(7)
#undef PC_STEP
      i += 16;
    }
    __syncthreads();                               // srt/hW reused next tile
  }

  red[tid] = acc;
  __syncthreads();
  if (part == 0) {                                 // combine 2 parts, write
    float s = red[tid] + red[tid + 32];
    int n = t * kNPB + l;
    int j = (n << kLogB) + b;
    if (mode == 0) {
      out[b * N + n] = s;                          // mu: 16 nodes = full 64B line
      eps_t[j] = x_t[j] - s;
    } else {
      float fx = fx_t[j];
      out[b * N + n] = fmaf(1.0f - fx * fx, s, -eps_t[j]);  // dx
    }
  }
}

extern "C" void kernel_launch(void* const* d_in, const int* in_sizes, int n_in,
                              void* d_out, int out_size, void* d_ws, size_t ws_size,
                              hipStream_t stream) {
  const float* x    = (const float*)d_in[0];
  const float* w    = (const float*)d_in[1];
  const int*   esrc = (const int*)d_in[2];
  const int*   edst = (const int*)d_in[3];

  int BN = in_sizes[0];                  // 131072
  int E  = in_sizes[1];                  // 524288
  int N  = BN / kB;                      // 4096
  int nBB = (E + kChunk - 1) / kChunk;   // 256
  int nTotal = nBB + (N >> 6);           // 320 blocks in k_hist

  float* ws    = (float*)d_ws;
  float* x_t   = ws;                     // [BN]
  float* fx_t  = ws + (size_t)BN;        // [BN]
  float* eps_t = ws + 2 * (size_t)BN;    // [BN]
  unsigned* cntA = (unsigned*)(ws + 3 * (size_t)BN);    // [nBB*256] 256 KB
  unsigned* cntB = cntA + (size_t)nBB * kBkt;
  unsigned* baseA = cntB + (size_t)nBB * kBkt;          // [nBB*256]
  unsigned* baseB = baseA + (size_t)nBB * kBkt;
  unsigned* segA = baseB + (size_t)nBB * kBkt;          // [257] (512 pad)
  unsigned* segB = segA + 512;
  unsigned* ctr  = segB + 512;                          // [1] arrival counter
  uint2* recA = (uint2*)(ctr + 512);                    // [E] 4 MB dense
  uint2* recB = recA + (size_t)E;                       // [E] 4 MB dense

  float* out_mu = (float*)d_out;
  float* out_dx = (float*)d_out + BN;

  // Zero the arrival counter (workspace is poisoned each iteration).
  hipMemsetAsync(ctr, 0, sizeof(unsigned), stream);

  k_hist<<<nTotal, 1024, 0, stream>>>(esrc, edst, x, x_t, fx_t,
                                      cntA, cntB, baseA, baseB, segA, segB,
                                      ctr, N, E, nBB, nTotal);
  k_scatter<<<nBB, 1024, 0, stream>>>(esrc, edst, w, cntA, cntB, baseA, baseB,
                                      recA, recB, E, nBB);
  // Pass 1: mu[n] = sum_{e: dst=n} w_e * fx[src_e]; eps = x - mu.
  k_pass<<<kBkt, 1024, 0, stream>>>(recA, segA, fx_t, x_t, fx_t,
                                    eps_t, out_mu, N, 0);
  // Pass 2: dx[n] = -eps[n] + f'(x_n) * sum_{e: src=n} w_e * eps[dst_e].
  k_pass<<<kBkt, 1024, 0, stream>>>(recB, segB, eps_t, x_t, fx_t,
                                    eps_t, out_dx, N, 1);
}

// Round 7
// 110.354 us; speedup vs baseline: 2.1673x; 1.0932x over previous
//
#include <hip/hip_runtime.h>

// Predictive-coding graph message passing, MI355X — round 17.
// R15/R16 lesson (twice-measured): device-scope ordering (grid.sync,
// __threadfence+arrival) costs 15-40us on MI355X (cross-XCD L2 writeback);
// kernel-launch boundaries are the cheapest barrier (~4us). So: R14's
// 5-dispatch fence-free skeleton (verified 107.5us) with ONE lever pulled —
// occupancy. R14 ran scatter & pass at 1 block/CU with long serialized
// phase chains (scatter: 2 dirs back-to-back; pass: stage/hist/sort/accum).
// R17 halves the serial path and puts 2 blocks/CU so phases overlap:
//   k_scatter: 512 blocks, one (direction,chunk) each (no dir loop).
//   k_pass:    512 blocks x 512 thr, half-bucket (8 nodes) each.
// Inner loops byte-identical to R14. k_hist/k_scan unchanged.

static constexpr int kB = 32, kLogB = 5;
static constexpr int kBkt = 256;        // coarse buckets (16 nodes each)
static constexpr int kNPB = 16;         // nodes per bucket
static constexpr int kChunk = 2048;     // edges per chunk block
static constexpr int kTile = 2560;      // pass LDS tile (mean 2048, +11sigma)

// ---- K1: per-chunk dual histograms + fused transpose/tanh. --------------
__global__ void __launch_bounds__(1024) k_hist(
    const int* __restrict__ esrc, const int* __restrict__ edst,
    const float* __restrict__ x, float* __restrict__ x_t,
    float* __restrict__ fx_t, unsigned* __restrict__ cntA,
    unsigned* __restrict__ cntB, int N, int E, int nBB) {
  __shared__ unsigned hA[kBkt], hB[kBkt];
  __shared__ float tile[32][65];
  int tid = threadIdx.x, blk = blockIdx.x;
  if (blk < nBB) {
    if (tid < kBkt) { hA[tid] = 0u; hB[tid] = 0u; }
    __syncthreads();
    int e0 = blk * kChunk, len = min(kChunk, E - e0);
    for (int i = tid; i < len; i += 1024) {
      atomicAdd(&hA[((unsigned)edst[e0 + i]) >> 4], 1u);  // ~8/bin: cheap
      atomicAdd(&hB[((unsigned)esrc[e0 + i]) >> 4], 1u);
    }
    __syncthreads();
    if (tid < kBkt) {                    // non-atomic coalesced row write
      cntA[(size_t)blk * kBkt + tid] = hA[tid];
      cntB[(size_t)blk * kBkt + tid] = hB[tid];
    }
  } else if (blk - nBB < (N >> 6)) {
    int n0 = (blk - nBB) * 64;
    for (int k = tid; k < 32 * 64; k += 1024) {  // coalesced 256B rows
      int b = k >> 6, n = k & 63;
      tile[b][n] = x[b * N + n0 + n];
    }
    __syncthreads();
    for (int k = tid; k < 64 * 32; k += 1024) {  // coalesced t-layout
      int n = k >> 5, b = k & 31;
      float xv = tile[b][n];
      int j = (n0 + n) * kB + b;
      x_t[j] = xv;
      fx_t[j] = tanhf(xv);
    }
  }
}

// ---- K2: scan [chunk][bucket] counts -> absolute bases + segment bounds.
__global__ void __launch_bounds__(1024) k_scan(
    const unsigned* __restrict__ cntA, const unsigned* __restrict__ cntB,
    unsigned* __restrict__ baseA, unsigned* __restrict__ baseB,
    unsigned* __restrict__ segA, unsigned* __restrict__ segB, int nBB) {
  __shared__ unsigned qoff[4][kBkt];
  __shared__ unsigned tot[kBkt];
  __shared__ unsigned bb[kBkt];
  const unsigned* cnt = blockIdx.x ? cntB : cntA;
  unsigned* base = blockIdx.x ? baseB : baseA;
  unsigned* seg  = blockIdx.x ? segB  : segA;
  int tid = threadIdx.x;
  int t = tid & (kBkt - 1), q = tid >> 8;
  int qlen = (nBB + 3) >> 2;
  int b0 = q * qlen;
  unsigned run = 0;
  for (int j = 0; j < qlen; j += 8) {
    unsigned c[8];
#pragma unroll
    for (int u = 0; u < 8; ++u) {        // 8 loads in flight
      int bi = b0 + j + u;
      c[u] = (bi < nBB) ? cnt[(size_t)bi * kBkt + t] : 0u;
    }
#pragma unroll
    for (int u = 0; u < 8; ++u) run += c[u];
  }
  qoff[q][t] = run;
  __syncthreads();
  unsigned myTot = 0;
  if (tid < kBkt) {                      // quarter offsets + bucket totals
    unsigned p0 = qoff[0][tid], p1 = qoff[1][tid];
    unsigned p2 = qoff[2][tid], p3 = qoff[3][tid];
    qoff[0][tid] = 0u; qoff[1][tid] = p0;
    qoff[2][tid] = p0 + p1; qoff[3][tid] = p0 + p1 + p2;
    myTot = p0 + p1 + p2 + p3;
    tot[tid] = myTot;
  }
  __syncthreads();
  for (int o = 1; o < kBkt; o <<= 1) {   // Hillis-Steele over 256 totals
    unsigned v = 0;
    if (tid < kBkt && tid >= o) v = tot[tid - o];
    __syncthreads();
    if (tid < kBkt && tid >= o) tot[tid] += v;
    __syncthreads();
  }
  if (tid < kBkt) {
    unsigned excl = tot[tid] - myTot;
    bb[tid] = excl;
    seg[tid] = excl;                     // dense segment starts
    if (tid == kBkt - 1) seg[kBkt] = excl + myTot;
  }
  __syncthreads();
  run = bb[t] + qoff[q][t];              // replay: absolute bases
  for (int j = 0; j < qlen; j += 8) {
    unsigned c[8];
#pragma unroll
    for (int u = 0; u < 8; ++u) {
      int bi = b0 + j + u;
      c[u] = (bi < nBB) ? cnt[(size_t)bi * kBkt + t] : 0u;
    }
#pragma unroll
    for (int u = 0; u < 8; ++u) {
      int bi = b0 + j + u;
      if (bi < nBB) base[(size_t)bi * kBkt + t] = run;
      run += c[u];
    }
  }
}

// ---- K3: deterministic scatter; 512 blocks, one (direction,chunk) each. -
__global__ void __launch_bounds__(1024) k_scatter(
    const int* __restrict__ esrc, const int* __restrict__ edst,
    const float* __restrict__ wgt,
    const unsigned* __restrict__ cntA, const unsigned* __restrict__ cntB,
    const unsigned* __restrict__ baseA, const unsigned* __restrict__ baseB,
    uint2* __restrict__ recA, uint2* __restrict__ recB, int E, int nBB) {
  __shared__ unsigned myBase[kBkt], cntL[kBkt], baseL[kBkt], cnt2[kBkt];
  __shared__ uint2 cmp[kChunk];          // 16 KB chunk-sorted records
  __shared__ unsigned char bktid[kChunk];
  int tid = threadIdx.x, blk = blockIdx.x;
  int dir = (blk >= nBB);
  int c = blk - (dir ? nBB : 0);
  int e0 = c * kChunk, len = min(kChunk, E - e0);
  const int* key = dir ? esrc : edst;    // A: by dst, B: by src
  const int* oth = dir ? edst : esrc;
  const unsigned* cnt = dir ? cntB : cntA;
  const unsigned* base = dir ? baseB : baseA;
  uint2* out = dir ? recB : recA;
  if (tid < kBkt) {
    myBase[tid] = base[(size_t)c * kBkt + tid];
    cntL[tid] = cnt[(size_t)c * kBkt + tid];
    cnt2[tid] = 0u;
  }
  __syncthreads();
  if (tid < 64) {                        // single-wave excl scan, 4 bins/lane
    int qq = tid << 2;
    unsigned c0 = cntL[qq], c1 = cntL[qq + 1];
    unsigned c2 = cntL[qq + 2], c3 = cntL[qq + 3];
    unsigned s = c0 + c1 + c2 + c3, run = s;
#pragma unroll
    for (int o = 1; o < 64; o <<= 1) {
      unsigned v = __shfl_up(run, o, 64);
      if (tid >= o) run += v;
    }
    unsigned bse = run - s;
    baseL[qq] = bse; baseL[qq + 1] = bse + c0;
    baseL[qq + 2] = bse + c0 + c1; baseL[qq + 3] = bse + c0 + c1 + c2;
  }
  __syncthreads();
  for (int i = tid; i < len; i += 1024) {          // LDS sort
    unsigned ky = (unsigned)key[e0 + i], ot = (unsigned)oth[e0 + i];
    unsigned bbk = ky >> 4;
    unsigned slot = baseL[bbk] + atomicAdd(&cnt2[bbk], 1u);
    cmp[slot] = make_uint2((ot << 4) | (ky & 15u), __float_as_uint(wgt[e0 + i]));
    bktid[slot] = (unsigned char)bbk;
  }
  __syncthreads();
  for (int s = tid; s < len; s += 1024) {          // coalesced run copy-out
    unsigned bbk = bktid[s];
    out[myBase[bbk] + ((unsigned)s - baseL[bbk])] = cmp[s];
  }
}

// ---- K4/K5: half-bucket fine sort + select-free pipelined accumulation. -
// 512 blocks x 512 thr: block owns 8 nodes (half=blk&1) of bucket t=blk>>1.
// 2 blocks/CU -> preamble/gather chains of co-resident blocks overlap.
// Inner pipeline identical to R14 (loads unconditional, clamped index;
// only the WEIGHT predicated — integer test, no memory dependence).
__global__ void __launch_bounds__(512) k_pass(
    const uint2* __restrict__ rec, const unsigned* __restrict__ seg,
    const float* __restrict__ vals, const float* __restrict__ x_t,
    const float* __restrict__ fx_t, float* __restrict__ eps_t,
    float* __restrict__ out, int N, int mode) {
  __shared__ uint2 srt[kTile];           // 20 KB node-sorted (this half only)
  __shared__ unsigned hW[8 * 8];         // per-wave private 8-bin hist
  __shared__ unsigned wbase[8 * 8];      // slot base per (wave,localnode)
  __shared__ unsigned wcur[8 * 8];
  __shared__ unsigned h[8], hb[8];
  __shared__ float red[512];
  int tid = threadIdx.x;
  int t = blockIdx.x >> 1, half = blockIdx.x & 1;
  int segb = (int)seg[t], sege = (int)seg[t + 1];
  int wv = tid >> 6;                     // wave 0..7
  int b = tid & 31, hw = tid >> 5, l3 = hw >> 1, part = hw & 1;
  unsigned lo8 = (unsigned)half << 3;
  float acc = 0.0f;

  for (int t0 = segb; t0 < sege; t0 += kTile) {    // 1 tile except 11-sigma tail
    int len = min(kTile, sege - t0);
    if (tid < 64) { hW[tid] = 0u; wcur[tid] = 0u; }
    __syncthreads();
    for (int i = tid; i < len; i += 512) {         // hist (kept records only)
      unsigned lx = rec[t0 + i].x & 15u;
      if ((lx >> 3) == (unsigned)half)
        atomicAdd(&hW[wv * 8 + (lx & 7u)], 1u);
    }
    __syncthreads();
    if (tid < 8) {                                 // cross-wave prefix per node
      unsigned run = 0;
#pragma unroll
      for (int w2 = 0; w2 < 8; ++w2) {
        unsigned cc = hW[w2 * 8 + tid];
        wbase[w2 * 8 + tid] = run;
        run += cc;
      }
      h[tid] = run;
    }
    __syncthreads();
    if (tid == 0) {                                // 8-elem excl scan
      unsigned run = 0;
#pragma unroll
      for (int l2 = 0; l2 < 8; ++l2) { hb[l2] = run; run += h[l2]; }
    }
    __syncthreads();
    if (tid < 64) wbase[tid] += hb[tid & 7];
    __syncthreads();
    for (int i = tid; i < len; i += 512) {         // fine sort (kept only)
      uint2 r = rec[t0 + i];                       // L2-warm re-read
      unsigned lx = r.x & 15u;
      if ((lx >> 3) == (unsigned)half)
        srt[wbase[wv * 8 + (lx & 7u)] + atomicAdd(&wcur[wv * 8 + (lx & 7u)], 1u)] = r;
    }
    __syncthreads();

    int beg = (int)hb[l3] + part, end = (int)hb[l3] + (int)h[l3];
    int last = end - 1; if (last < 0) last = 0;
    uint2 r0, r1, r2, r3, r4, r5, r6, r7;
    float v0, v1, v2, v3, v4, v5, v6, v7;
#define PC_LOAD(d)                                                   \
    { int p = beg + 2 * (d); uint2 rr = srt[min(p, last)];           \
      r##d = rr; v##d = vals[(((rr.x >> 4) & 4095u) << kLogB) + b]; }
    PC_LOAD(0) PC_LOAD(1) PC_LOAD(2) PC_LOAD(3)
    PC_LOAD(4) PC_LOAD(5) PC_LOAD(6) PC_LOAD(7)
#undef PC_LOAD
    int i = beg;
    while (i < end) {
#define PC_STEP(d)                                                   \
      { float wt = (i + 2 * (d) < end) ? __uint_as_float(r##d.y) : 0.0f; \
        acc = fmaf(wt, v##d, acc);                                   \
        int p = i + 16 + 2 * (d); uint2 rr = srt[min(p, last)];      \
        r##d = rr; v##d = vals[(((rr.x >> 4) & 4095u) << kLogB) + b]; }
      PC_STEP(0) PC_STEP(1) PC_STEP(2) PC_STEP(3)
      PC_STEP(4) PC_STEP(5) PC_STEP(6) PC_STEP(7)
#undef PC_STEP
      i += 16;
    }
    __syncthreads();                               // srt/hW reused next tile
  }

  red[tid] = acc;
  __syncthreads();
  if (part == 0) {                                 // combine 2 parts, write
    float s = red[tid] + red[tid + 32];
    int n = t * kNPB + (int)lo8 + l3;
    int j = (n << kLogB) + b;
    if (mode == 0) {
      out[b * N + n] = s;                          // mu (batch-major)
      eps_t[j] = x_t[j] - s;
    } else {
      float fx = fx_t[j];
      out[b * N + n] = fmaf(1.0f - fx * fx, s, -eps_t[j]);  // dx
    }
  }
}

extern "C" void kernel_launch(void* const* d_in, const int* in_sizes, int n_in,
                              void* d_out, int out_size, void* d_ws, size_t ws_size,
                              hipStream_t stream) {
  const float* x    = (const float*)d_in[0];
  const float* w    = (const float*)d_in[1];
  const int*   esrc = (const int*)d_in[2];
  const int*   edst = (const int*)d_in[3];

  int BN = in_sizes[0];                  // 131072
  int E  = in_sizes[1];                  // 524288
  int N  = BN / kB;                      // 4096
  int nBB = (E + kChunk - 1) / kChunk;   // 256

  float* ws    = (float*)d_ws;
  float* x_t   = ws;                     // [BN]
  float* fx_t  = ws + (size_t)BN;        // [BN]
  float* eps_t = ws + 2 * (size_t)BN;    // [BN]
  unsigned* cntA = (unsigned*)(ws + 3 * (size_t)BN);    // [nBB*256] 256 KB
  unsigned* cntB = cntA + (size_t)nBB * kBkt;
  unsigned* baseA = cntB + (size_t)nBB * kBkt;          // [nBB*256]
  unsigned* baseB = baseA + (size_t)nBB * kBkt;
  unsigned* segA = baseB + (size_t)nBB * kBkt;          // [257] (512 pad)
  unsigned* segB = segA + 512;
  uint2* recA = (uint2*)(segB + 512);                   // [E] 4 MB dense
  uint2* recB = recA + (size_t)E;                       // [E] 4 MB dense

  float* out_mu = (float*)d_out;
  float* out_dx = (float*)d_out + BN;

  k_hist<<<nBB + (N >> 6), 1024, 0, stream>>>(esrc, edst, x, x_t, fx_t,
                                              cntA, cntB, N, E, nBB);
  k_scan<<<2, 1024, 0, stream>>>(cntA, cntB, baseA, baseB, segA, segB, nBB);
  k_scatter<<<2 * nBB, 1024, 0, stream>>>(esrc, edst, w, cntA, cntB,
                                          baseA, baseB, recA, recB, E, nBB);
  // Pass 1: mu[n] = sum_{e: dst=n} w_e * fx[src_e]; eps = x - mu.
  k_pass<<<2 * kBkt, 512, 0, stream>>>(recA, segA, fx_t, x_t, fx_t,
                                       eps_t, out_mu, N, 0);
  // Pass 2: dx[n] = -eps[n] + f'(x_n) * sum_{e: src=n} w_e * eps[dst_e].
  k_pass<<<2 * kBkt, 512, 0, stream>>>(recB, segB, eps_t, x_t, fx_t,
                                       eps_t, out_dx, N, 1);
}